// Round 1
// baseline (5768.592 us; speedup 1.0000x reference)
//
#include <hip/hip_runtime.h>

// GCN 2-layer forward, MI355X baseline (round 0: correctness-first, fp32 throughout)
// Pipeline: deg/norm -> GEMM1 -> edge-scatter-agg1 -> post1(selfloop+bias+relu)
//           -> GEMM2 -> edge-scatter-agg2 -> post2(selfloop+bias)

#define DIM 128

// ---------------------------------------------------------------- degree/norm
__global__ __launch_bounds__(256) void k_deg_init(float* __restrict__ deg, int n) {
    int i = blockIdx.x * 256 + threadIdx.x;
    if (i < n) deg[i] = 1.0f;   // self-loop contributes 1 to every node's degree
}

__global__ __launch_bounds__(256) void k_deg_count(const int* __restrict__ dst,
                                                   float* __restrict__ deg, int E) {
    int e = blockIdx.x * 256 + threadIdx.x;
    if (e < E) atomicAdd(&deg[dst[e]], 1.0f);
}

__global__ __launch_bounds__(256) void k_rsqrt(float* __restrict__ deg, int n) {
    int i = blockIdx.x * 256 + threadIdx.x;
    if (i < n) deg[i] = rsqrtf(deg[i]);   // deg >= 1 always (self-loops)
}

// ---------------------------------------------------------------- fp32 GEMM
// C[M x 128] = A[M x 128] * W[128 x 128]; block = 256 threads, 128 rows/block.
// XS row-major padded to 132 (float4-aligned rows, 2-way max conflicts on the
// strided scalar reads); WS row-major unpadded (b128 reads are 2-way broadcast).
__global__ __launch_bounds__(256) void k_gemm(const float* __restrict__ A,
                                              const float* __restrict__ W,
                                              float* __restrict__ C, int M) {
    __shared__ float XS[128][132];
    __shared__ float WS[128][128];
    const int t = threadIdx.x;
    const int row0 = blockIdx.x << 7;

    // stage W: 4096 float4s / 256 threads = 16 each, coalesced
    #pragma unroll
    for (int i = 0; i < 16; ++i) {
        int f = (i << 8) + t;
        int k = f >> 5, q = f & 31;
        *(float4*)(&WS[k][q << 2]) = ((const float4*)W)[f];
    }
    // stage X tile (row-major; guard tail rows with zeros)
    #pragma unroll
    for (int i = 0; i < 16; ++i) {
        int f = (i << 8) + t;
        int r = f >> 5, q = f & 31;
        int gr = row0 + r;
        float4 v = make_float4(0.f, 0.f, 0.f, 0.f);
        if (gr < M) v = ((const float4*)A)[(gr << 5) + q];
        *(float4*)(&XS[r][q << 2]) = v;   // row stride 528B = 33*16 -> aligned
    }
    __syncthreads();

    const int tr = (t >> 4) << 2;   // row base 0..60
    const int tc = (t & 15) << 2;   // col base 0..60
    float acc[2][2][4][4] = {};     // [rr][cc][i][j]: rows tr+64rr+i, cols tc+64cc+j

    for (int k = 0; k < 128; ++k) {
        float xa[2][4];
        float4 wb[2];
        #pragma unroll
        for (int rr = 0; rr < 2; ++rr)
            #pragma unroll
            for (int i = 0; i < 4; ++i)
                xa[rr][i] = XS[tr + (rr << 6) + i][k];
        #pragma unroll
        for (int cc = 0; cc < 2; ++cc)
            wb[cc] = *(const float4*)(&WS[k][tc + (cc << 6)]);
        #pragma unroll
        for (int rr = 0; rr < 2; ++rr)
            #pragma unroll
            for (int i = 0; i < 4; ++i) {
                float a = xa[rr][i];
                #pragma unroll
                for (int cc = 0; cc < 2; ++cc) {
                    acc[rr][cc][i][0] += a * wb[cc].x;
                    acc[rr][cc][i][1] += a * wb[cc].y;
                    acc[rr][cc][i][2] += a * wb[cc].z;
                    acc[rr][cc][i][3] += a * wb[cc].w;
                }
            }
    }

    #pragma unroll
    for (int rr = 0; rr < 2; ++rr)
        #pragma unroll
        for (int i = 0; i < 4; ++i) {
            int gr = row0 + tr + (rr << 6) + i;
            if (gr < M) {
                #pragma unroll
                for (int cc = 0; cc < 2; ++cc) {
                    float4 v = make_float4(acc[rr][cc][i][0], acc[rr][cc][i][1],
                                           acc[rr][cc][i][2], acc[rr][cc][i][3]);
                    *(float4*)(&C[(gr << 7) + tc + (cc << 6)]) = v;
                }
            }
        }
}

// ---------------------------------------------------------------- aggregation
// 32 threads per edge; each thread handles 4 columns (float4 gather + 4 atomics).
__global__ __launch_bounds__(256) void k_agg(const float* __restrict__ h,
                                             const int* __restrict__ src,
                                             const int* __restrict__ dst,
                                             const float* __restrict__ dinv,
                                             float* __restrict__ out, int E) {
    int tid = blockIdx.x * 256 + threadIdx.x;
    int e = tid >> 5;
    if (e >= E) return;
    int lane = tid & 31;
    int s = src[e], d = dst[e];
    float w = dinv[s] * dinv[d];
    float4 v = ((const float4*)h)[(s << 5) + lane];
    float* o = out + (d << 7) + (lane << 2);
    atomicAdd(o + 0, v.x * w);
    atomicAdd(o + 1, v.y * w);
    atomicAdd(o + 2, v.z * w);
    atomicAdd(o + 3, v.w * w);
}

// ------------------------------------------------- self-loop + bias (+ relu)
// agg[i] = act(agg[i] + dinv[n]^2 * h[i] + b[c]); in place, float4 granularity.
__global__ __launch_bounds__(256) void k_post(const float* __restrict__ h,
                                              const float* __restrict__ dinv,
                                              const float* __restrict__ bias,
                                              float* __restrict__ agg,
                                              int n4, int relu) {
    int i = blockIdx.x * 256 + threadIdx.x;   // float4 index over N*32
    if (i >= n4) return;
    int n = i >> 5, q = i & 31;
    float di = dinv[n];
    float w = di * di;
    float4 hv = ((const float4*)h)[i];
    float4 av = ((float4*)agg)[i];
    float4 bv = ((const float4*)bias)[q];
    float4 r;
    r.x = av.x + w * hv.x + bv.x;
    r.y = av.y + w * hv.y + bv.y;
    r.z = av.z + w * hv.z + bv.z;
    r.w = av.w + w * hv.w + bv.w;
    if (relu) {
        r.x = fmaxf(r.x, 0.f); r.y = fmaxf(r.y, 0.f);
        r.z = fmaxf(r.z, 0.f); r.w = fmaxf(r.w, 0.f);
    }
    ((float4*)agg)[i] = r;
}

// ---------------------------------------------------------------- launch
extern "C" void kernel_launch(void* const* d_in, const int* in_sizes, int n_in,
                              void* d_out, int out_size, void* d_ws, size_t ws_size,
                              hipStream_t stream) {
    const float* x  = (const float*)d_in[0];
    const int*   ei = (const int*)d_in[1];
    const float* W1 = (const float*)d_in[2];
    const float* b1 = (const float*)d_in[3];
    const float* W2 = (const float*)d_in[4];
    const float* b2 = (const float*)d_in[5];
    float* out = (float*)d_out;

    const int N = in_sizes[0] / DIM;        // 100000
    const int E = in_sizes[1] / 2;          // 1600000
    const int* src = ei;
    const int* dst = ei + E;

    const size_t NB = (size_t)N * DIM * sizeof(float);   // 51.2 MB
    float* deg   = (float*)d_ws;                                       // N floats (becomes dinv)
    float* buf_h = (float*)((char*)d_ws + (1 << 20));                  // GEMM output (both layers)
    float* buf_a = (float*)((char*)d_ws + (1 << 20) + NB);             // layer-1 aggregation

    const int B = 256;
    const int n4 = N * (DIM / 4);           // float4 count per feature matrix

    // zero accumulation targets (harness poisons ws/out with 0xAA each call)
    hipMemsetAsync(buf_a, 0, NB, stream);
    hipMemsetAsync(out,   0, NB, stream);

    // degree -> dinv
    k_deg_init<<<(N + B - 1) / B, B, 0, stream>>>(deg, N);
    k_deg_count<<<(E + B - 1) / B, B, 0, stream>>>(dst, deg, E);
    k_rsqrt<<<(N + B - 1) / B, B, 0, stream>>>(deg, N);

    const int gemm_grid = (N + 127) / 128;

    // layer 1
    k_gemm<<<gemm_grid, B, 0, stream>>>(x, W1, buf_h, N);
    k_agg<<<(E * 32 + B - 1) / B, B, 0, stream>>>(buf_h, src, dst, deg, buf_a, E);
    k_post<<<(n4 + B - 1) / B, B, 0, stream>>>(buf_h, deg, b1, buf_a, n4, 1);

    // layer 2
    k_gemm<<<gemm_grid, B, 0, stream>>>(buf_a, W2, buf_h, N);
    k_agg<<<(E * 32 + B - 1) / B, B, 0, stream>>>(buf_h, src, dst, deg, out, E);
    k_post<<<(n4 + B - 1) / B, B, 0, stream>>>(buf_h, deg, b2, out, n4, 0);
}

// Round 2
// 701.242 us; speedup vs baseline: 8.2262x; 8.2262x over previous
//
#include <hip/hip_runtime.h>

// GCN 2-layer forward, MI355X round 1: CSR-by-dst build + gather aggregation
// (replaces 204.8M fp32 scatter-atomics -> one coalesced store per node row).
// Pipeline: hist(dst) -> dinv -> scan -> bucket-scatter ->
//           [GEMM -> fused gather-agg(selfloop+bias+relu)] x 2

#define DIM 128

// ---------------------------------------------------------------- histogram
__global__ __launch_bounds__(256) void k_hist(const int* __restrict__ dst,
                                              int* __restrict__ cnt, int E) {
    int e = blockIdx.x * 256 + threadIdx.x;
    if (e < E) atomicAdd(&cnt[dst[e]], 1);
}

__global__ __launch_bounds__(256) void k_dinv(const int* __restrict__ cnt,
                                              float* __restrict__ dinv, int n) {
    int i = blockIdx.x * 256 + threadIdx.x;
    if (i < n) dinv[i] = rsqrtf((float)cnt[i] + 1.0f);  // +1 self-loop
}

// ------------------------------------------------- 2-level exclusive scan
// scan1: per-block (256) inclusive scan; writes exclusive values + block sum
__global__ __launch_bounds__(256) void k_scan1(const int* __restrict__ cnt,
                                               int* __restrict__ off,
                                               int* __restrict__ bsum, int n) {
    __shared__ int s[256];
    int t = threadIdx.x;
    int i = blockIdx.x * 256 + t;
    int v = (i < n) ? cnt[i] : 0;
    s[t] = v;
    __syncthreads();
    #pragma unroll
    for (int o = 1; o < 256; o <<= 1) {
        int x = (t >= o) ? s[t - o] : 0;
        __syncthreads();
        s[t] += x;
        __syncthreads();
    }
    if (i < n) off[i] = s[t] - v;          // exclusive
    if (t == 0) bsum[blockIdx.x] = s[255]; // block total
}

// scan2: single block, exclusive scan of <=512 block sums in place
__global__ __launch_bounds__(512) void k_scan2(int* __restrict__ bsum, int nb) {
    __shared__ int s[512];
    int t = threadIdx.x;
    int v = (t < nb) ? bsum[t] : 0;
    s[t] = v;
    __syncthreads();
    #pragma unroll
    for (int o = 1; o < 512; o <<= 1) {
        int x = (t >= o) ? s[t - o] : 0;
        __syncthreads();
        s[t] += x;
        __syncthreads();
    }
    if (t < nb) bsum[t] = s[t] - v;        // exclusive
}

// scan3: add block offsets; thread 0 writes off[n] = E
__global__ __launch_bounds__(256) void k_scan3(int* __restrict__ off,
                                               const int* __restrict__ bsum,
                                               int n, int E) {
    int i = blockIdx.x * 256 + threadIdx.x;
    if (i < n) off[i] += bsum[blockIdx.x];
    if (i == 0) off[n] = E;
}

// ---------------------------------------------------- bucket scatter to CSR
__global__ __launch_bounds__(256) void k_scatter(const int* __restrict__ src,
                                                 const int* __restrict__ dst,
                                                 const int* __restrict__ off,
                                                 int* __restrict__ cur,
                                                 const float* __restrict__ dinv,
                                                 int* __restrict__ csr_src,
                                                 float* __restrict__ csr_w, int E) {
    int e = blockIdx.x * 256 + threadIdx.x;
    if (e >= E) return;
    int s = src[e], d = dst[e];
    int pos = off[d] + atomicAdd(&cur[d], 1);
    csr_src[pos] = s;
    csr_w[pos] = dinv[s] * dinv[d];
}

// ---------------------------------------------------------------- fp32 GEMM
// C[M x 128] = A[M x 128] * W[128 x 128]; block = 256 threads, 128 rows/block.
__global__ __launch_bounds__(256) void k_gemm(const float* __restrict__ A,
                                              const float* __restrict__ W,
                                              float* __restrict__ C, int M) {
    __shared__ float XS[128][132];
    __shared__ float WS[128][128];
    const int t = threadIdx.x;
    const int row0 = blockIdx.x << 7;

    #pragma unroll
    for (int i = 0; i < 16; ++i) {
        int f = (i << 8) + t;
        int k = f >> 5, q = f & 31;
        *(float4*)(&WS[k][q << 2]) = ((const float4*)W)[f];
    }
    #pragma unroll
    for (int i = 0; i < 16; ++i) {
        int f = (i << 8) + t;
        int r = f >> 5, q = f & 31;
        int gr = row0 + r;
        float4 v = make_float4(0.f, 0.f, 0.f, 0.f);
        if (gr < M) v = ((const float4*)A)[(gr << 5) + q];
        *(float4*)(&XS[r][q << 2]) = v;
    }
    __syncthreads();

    const int tr = (t >> 4) << 2;
    const int tc = (t & 15) << 2;
    float acc[2][2][4][4] = {};

    for (int k = 0; k < 128; ++k) {
        float xa[2][4];
        float4 wb[2];
        #pragma unroll
        for (int rr = 0; rr < 2; ++rr)
            #pragma unroll
            for (int i = 0; i < 4; ++i)
                xa[rr][i] = XS[tr + (rr << 6) + i][k];
        #pragma unroll
        for (int cc = 0; cc < 2; ++cc)
            wb[cc] = *(const float4*)(&WS[k][tc + (cc << 6)]);
        #pragma unroll
        for (int rr = 0; rr < 2; ++rr)
            #pragma unroll
            for (int i = 0; i < 4; ++i) {
                float a = xa[rr][i];
                #pragma unroll
                for (int cc = 0; cc < 2; ++cc) {
                    acc[rr][cc][i][0] += a * wb[cc].x;
                    acc[rr][cc][i][1] += a * wb[cc].y;
                    acc[rr][cc][i][2] += a * wb[cc].z;
                    acc[rr][cc][i][3] += a * wb[cc].w;
                }
            }
    }

    #pragma unroll
    for (int rr = 0; rr < 2; ++rr)
        #pragma unroll
        for (int i = 0; i < 4; ++i) {
            int gr = row0 + tr + (rr << 6) + i;
            if (gr < M) {
                #pragma unroll
                for (int cc = 0; cc < 2; ++cc) {
                    float4 v = make_float4(acc[rr][cc][i][0], acc[rr][cc][i][1],
                                           acc[rr][cc][i][2], acc[rr][cc][i][3]);
                    *(float4*)(&C[(gr << 7) + tc + (cc << 6)]) = v;
                }
            }
        }
}

// ------------------------------------------- gather aggregation, fully fused
// One wave (64 lanes) per node; lane handles 2 cols (float2 -> 512B/edge read).
// out[n] = act( sum_e w_e * h[src_e] + dinv[n]^2 * h[n] + bias )
__global__ __launch_bounds__(256) void k_agg(const float* __restrict__ h,
                                             const int* __restrict__ off,
                                             const int* __restrict__ csr_src,
                                             const float* __restrict__ csr_w,
                                             const float* __restrict__ dinv,
                                             const float* __restrict__ bias,
                                             float* __restrict__ out,
                                             int N, int relu) {
    int n = (blockIdx.x * 256 + threadIdx.x) >> 6;
    if (n >= N) return;
    int l = threadIdx.x & 63;
    const float2* h2 = (const float2*)h;

    float di = dinv[n];
    float2 acc = h2[(n << 6) + l];          // self-loop term
    acc.x *= di * di;
    acc.y *= di * di;

    int e = off[n], end = off[n + 1];
    // unroll-4: 4 independent gathers in flight
    for (; e + 4 <= end; e += 4) {
        int s0 = csr_src[e + 0], s1 = csr_src[e + 1];
        int s2 = csr_src[e + 2], s3 = csr_src[e + 3];
        float w0 = csr_w[e + 0], w1 = csr_w[e + 1];
        float w2 = csr_w[e + 2], w3 = csr_w[e + 3];
        float2 v0 = h2[(s0 << 6) + l];
        float2 v1 = h2[(s1 << 6) + l];
        float2 v2 = h2[(s2 << 6) + l];
        float2 v3 = h2[(s3 << 6) + l];
        acc.x += w0 * v0.x + w1 * v1.x + w2 * v2.x + w3 * v3.x;
        acc.y += w0 * v0.y + w1 * v1.y + w2 * v2.y + w3 * v3.y;
    }
    for (; e < end; ++e) {
        int s = csr_src[e];
        float w = csr_w[e];
        float2 v = h2[(s << 6) + l];
        acc.x += w * v.x;
        acc.y += w * v.y;
    }

    float2 bv = ((const float2*)bias)[l];
    acc.x += bv.x;
    acc.y += bv.y;
    if (relu) {
        acc.x = fmaxf(acc.x, 0.f);
        acc.y = fmaxf(acc.y, 0.f);
    }
    ((float2*)out)[(n << 6) + l] = acc;
}

// ---------------------------------------------------------------- launch
extern "C" void kernel_launch(void* const* d_in, const int* in_sizes, int n_in,
                              void* d_out, int out_size, void* d_ws, size_t ws_size,
                              hipStream_t stream) {
    const float* x  = (const float*)d_in[0];
    const int*   ei = (const int*)d_in[1];
    const float* W1 = (const float*)d_in[2];
    const float* b1 = (const float*)d_in[3];
    const float* W2 = (const float*)d_in[4];
    const float* b2 = (const float*)d_in[5];
    float* out = (float*)d_out;

    const int N = in_sizes[0] / DIM;        // 100000
    const int E = in_sizes[1] / 2;          // 1600000
    const int* src = ei;
    const int* dst = ei + E;

    // workspace layout
    char* w = (char*)d_ws;
    float* dinv    = (float*)(w);                      // 400 KB
    int*   cnt     = (int*)  (w + (1 << 19));          // 400 KB (hist, then cursor)
    int*   off     = (int*)  (w + (2 << 19));          // 400 KB (+4)
    int*   bsum    = (int*)  (w + (3 << 19));          // 2 KB
    int*   csr_src = (int*)  (w + (4 << 19));          // 6.4 MB
    float* csr_w   = (float*)(w + (4 << 19) + (8 << 20)); // 6.4 MB
    float* buf_h   = (float*)(w + (4 << 19) + (16 << 20));            // 51.2 MB
    float* buf_a   = (float*)(w + (4 << 19) + (16 << 20) + ((size_t)N * DIM * 4));

    const int B = 256;
    const int nb = (N + 255) / 256;         // scan blocks (391 <= 512)

    // CSR build
    hipMemsetAsync(cnt, 0, (size_t)N * 4, stream);
    k_hist<<<(E + B - 1) / B, B, 0, stream>>>(dst, cnt, E);
    k_dinv<<<nb, B, 0, stream>>>(cnt, dinv, N);
    k_scan1<<<nb, B, 0, stream>>>(cnt, off, bsum, N);
    k_scan2<<<1, 512, 0, stream>>>(bsum, nb);
    k_scan3<<<nb, B, 0, stream>>>(off, bsum, N, E);
    hipMemsetAsync(cnt, 0, (size_t)N * 4, stream);     // reuse as cursor
    k_scatter<<<(E + B - 1) / B, B, 0, stream>>>(src, dst, off, cnt, dinv,
                                                 csr_src, csr_w, E);

    const int gemm_grid = (N + 127) / 128;
    const int agg_grid = (N * 64 + B - 1) / B;         // one wave per node

    // layer 1
    k_gemm<<<gemm_grid, B, 0, stream>>>(x, W1, buf_h, N);
    k_agg<<<agg_grid, B, 0, stream>>>(buf_h, off, csr_src, csr_w, dinv, b1,
                                      buf_a, N, 1);
    // layer 2
    k_gemm<<<gemm_grid, B, 0, stream>>>(buf_a, W2, buf_h, N);
    k_agg<<<agg_grid, B, 0, stream>>>(buf_h, off, csr_src, csr_w, dinv, b2,
                                      out, N, 0);
}

// Round 3
// 562.499 us; speedup vs baseline: 10.2553x; 1.2467x over previous
//
#include <hip/hip_runtime.h>

// GCN 2-layer forward, MI355X round 2: split-bf16 MFMA GEMM (ah*bh+ah*bl+al*bh,
// fp32 acc -> ~2^-17 rel error) replaces fp32 vector GEMM. CSR gather agg kept.

#define DIM 128

typedef __attribute__((ext_vector_type(8))) short bf16x8;   // 8 bf16 = 4 VGPRs
typedef __attribute__((ext_vector_type(4))) float f32x4;

static __device__ __forceinline__ unsigned short f2bf(float f) {
    union { float f; unsigned u; } c; c.f = f;
    unsigned u = c.u;
    return (unsigned short)((u + 0x7FFFu + ((u >> 16) & 1u)) >> 16);   // RN
}
static __device__ __forceinline__ float bf2f(unsigned short h) {
    union { unsigned u; float f; } c; c.u = ((unsigned)h) << 16;
    return c.f;
}

// ---------------------------------------------------------------- histogram
__global__ __launch_bounds__(256) void k_hist(const int* __restrict__ dst,
                                              int* __restrict__ cnt, int E) {
    int e = blockIdx.x * 256 + threadIdx.x;
    if (e < E) atomicAdd(&cnt[dst[e]], 1);
}

__global__ __launch_bounds__(256) void k_dinv(const int* __restrict__ cnt,
                                              float* __restrict__ dinv, int n) {
    int i = blockIdx.x * 256 + threadIdx.x;
    if (i < n) dinv[i] = rsqrtf((float)cnt[i] + 1.0f);  // +1 self-loop
}

// ------------------------------------------------- 2-level exclusive scan
__global__ __launch_bounds__(256) void k_scan1(const int* __restrict__ cnt,
                                               int* __restrict__ off,
                                               int* __restrict__ bsum, int n) {
    __shared__ int s[256];
    int t = threadIdx.x;
    int i = blockIdx.x * 256 + t;
    int v = (i < n) ? cnt[i] : 0;
    s[t] = v;
    __syncthreads();
    #pragma unroll
    for (int o = 1; o < 256; o <<= 1) {
        int x = (t >= o) ? s[t - o] : 0;
        __syncthreads();
        s[t] += x;
        __syncthreads();
    }
    if (i < n) off[i] = s[t] - v;
    if (t == 0) bsum[blockIdx.x] = s[255];
}

__global__ __launch_bounds__(512) void k_scan2(int* __restrict__ bsum, int nb) {
    __shared__ int s[512];
    int t = threadIdx.x;
    int v = (t < nb) ? bsum[t] : 0;
    s[t] = v;
    __syncthreads();
    #pragma unroll
    for (int o = 1; o < 512; o <<= 1) {
        int x = (t >= o) ? s[t - o] : 0;
        __syncthreads();
        s[t] += x;
        __syncthreads();
    }
    if (t < nb) bsum[t] = s[t] - v;
}

__global__ __launch_bounds__(256) void k_scan3(int* __restrict__ off,
                                               const int* __restrict__ bsum,
                                               int n, int E) {
    int i = blockIdx.x * 256 + threadIdx.x;
    if (i < n) off[i] += bsum[blockIdx.x];
    if (i == 0) off[n] = E;
}

// ---------------------------------------------------- bucket scatter to CSR
__global__ __launch_bounds__(256) void k_scatter(const int* __restrict__ src,
                                                 const int* __restrict__ dst,
                                                 const int* __restrict__ off,
                                                 int* __restrict__ cur,
                                                 const float* __restrict__ dinv,
                                                 int* __restrict__ csr_src,
                                                 float* __restrict__ csr_w, int E) {
    int e = blockIdx.x * 256 + threadIdx.x;
    if (e >= E) return;
    int s = src[e], d = dst[e];
    int pos = off[d] + atomicAdd(&cur[d], 1);
    csr_src[pos] = s;
    csr_w[pos] = dinv[s] * dinv[d];
}

// -------------------------------------------- W -> fragment-ready bf16 hi/lo
// Layout: [layer][ks(4)][nt(8)][lane(64)][j(8)] ; frag B[k=ks*32+(l>>4)*8+j][n=nt*16+(l&15)]
__global__ __launch_bounds__(256) void k_prep_w(const float* __restrict__ W1,
                                                const float* __restrict__ W2,
                                                short* __restrict__ whi,
                                                short* __restrict__ wlo) {
    int g = blockIdx.x * 256 + threadIdx.x;      // 0..4095
    int layer = g >> 11, c = g & 2047;
    const float* W = layer ? W2 : W1;
    int ks = c >> 9, nt = (c >> 6) & 7, l = c & 63;
    int q = l >> 4, m = l & 15;
    int n = nt * 16 + m;
    bf16x8 h8, l8;
    #pragma unroll
    for (int j = 0; j < 8; ++j) {
        int k = ks * 32 + q * 8 + j;
        float f = W[k * 128 + n];
        unsigned short hb = f2bf(f);
        h8[j] = (short)hb;
        l8[j] = (short)f2bf(f - bf2f(hb));
    }
    ((bf16x8*)whi)[(size_t)layer * 2048 + c] = h8;
    ((bf16x8*)wlo)[(size_t)layer * 2048 + c] = l8;
}

// ------------------------------------------------- split-bf16 MFMA GEMM
// C[M x 128] = A[M x 128] * W ; 256 thr, 128 rows/block, K staged in 2 halves.
// LDS 64 KB -> 2 blocks/CU. Wave computes 32 rows x 128 cols via 16x16x32 MFMA.
__global__ __launch_bounds__(256) void k_gemm(const float* __restrict__ A,
                                              const short* __restrict__ whi,
                                              const short* __restrict__ wlo,
                                              float* __restrict__ C, int M) {
    __shared__ short AH[2][8][64][8];   // [ksl][mtile][lane][j] 16 KB
    __shared__ short AL[2][8][64][8];
    __shared__ short WHs[2][8][64][8];  // [ksl][ntile][lane][j]
    __shared__ short WLs[2][8][64][8];

    const int t = threadIdx.x;
    const int row0 = blockIdx.x << 7;
    const int wave = t >> 6, l = t & 63;
    const int row = t >> 1, half = t & 1;
    const int mt = row >> 4, mloc = row & 15;
    const int grow = row0 + row;
    const bool rowok = grow < M;
    const float4* X4 = (const float4*)A;

    f32x4 acc[2][8];
    #pragma unroll
    for (int a = 0; a < 2; ++a)
        #pragma unroll
        for (int b = 0; b < 8; ++b)
            acc[a][b] = (f32x4){0.f, 0.f, 0.f, 0.f};

    #pragma unroll
    for (int kc = 0; kc < 2; ++kc) {
        if (kc) __syncthreads();   // all reads of pass-0 LDS done
        // stage A: 64 k-floats of this row-half, split to hi/lo frag chunks
        #pragma unroll
        for (int cc = 0; cc < 4; ++cc) {
            float4 fa = make_float4(0.f, 0.f, 0.f, 0.f);
            float4 fb = fa;
            if (rowok) {
                int base = grow * 32 + kc * 16 + half * 8 + cc * 2;
                fa = X4[base];
                fb = X4[base + 1];
            }
            float f[8] = {fa.x, fa.y, fa.z, fa.w, fb.x, fb.y, fb.z, fb.w};
            bf16x8 h8, l8;
            #pragma unroll
            for (int j = 0; j < 8; ++j) {
                unsigned short hb = f2bf(f[j]);
                h8[j] = (short)hb;
                l8[j] = (short)f2bf(f[j] - bf2f(hb));
            }
            *(bf16x8*)&AH[half][mt][cc * 16 + mloc][0] = h8;
            *(bf16x8*)&AL[half][mt][cc * 16 + mloc][0] = l8;
        }
        // stage W frags (already fragment-ready in global): 1024 vecs/pass
        {
            const bf16x8* GH = (const bf16x8*)whi + kc * 1024;
            const bf16x8* GL = (const bf16x8*)wlo + kc * 1024;
            bf16x8* SH = (bf16x8*)WHs;
            bf16x8* SL = (bf16x8*)WLs;
            #pragma unroll
            for (int i = 0; i < 4; ++i) {
                SH[t + 256 * i] = GH[t + 256 * i];
                SL[t + 256 * i] = GL[t + 256 * i];
            }
        }
        __syncthreads();
        // compute this K-half
        #pragma unroll
        for (int ksl = 0; ksl < 2; ++ksl) {
            bf16x8 ah0 = *(const bf16x8*)&AH[ksl][2 * wave + 0][l][0];
            bf16x8 al0 = *(const bf16x8*)&AL[ksl][2 * wave + 0][l][0];
            bf16x8 ah1 = *(const bf16x8*)&AH[ksl][2 * wave + 1][l][0];
            bf16x8 al1 = *(const bf16x8*)&AL[ksl][2 * wave + 1][l][0];
            #pragma unroll
            for (int nt = 0; nt < 8; ++nt) {
                bf16x8 bh = *(const bf16x8*)&WHs[ksl][nt][l][0];
                bf16x8 bl = *(const bf16x8*)&WLs[ksl][nt][l][0];
                acc[0][nt] = __builtin_amdgcn_mfma_f32_16x16x32_bf16(ah0, bh, acc[0][nt], 0, 0, 0);
                acc[0][nt] = __builtin_amdgcn_mfma_f32_16x16x32_bf16(al0, bh, acc[0][nt], 0, 0, 0);
                acc[0][nt] = __builtin_amdgcn_mfma_f32_16x16x32_bf16(ah0, bl, acc[0][nt], 0, 0, 0);
                acc[1][nt] = __builtin_amdgcn_mfma_f32_16x16x32_bf16(ah1, bh, acc[1][nt], 0, 0, 0);
                acc[1][nt] = __builtin_amdgcn_mfma_f32_16x16x32_bf16(al1, bh, acc[1][nt], 0, 0, 0);
                acc[1][nt] = __builtin_amdgcn_mfma_f32_16x16x32_bf16(ah1, bl, acc[1][nt], 0, 0, 0);
            }
        }
    }

    // store: C/D layout col = lane&15, row = (lane>>4)*4 + reg
    const int q = l >> 4, mm = l & 15;
    #pragma unroll
    for (int mi = 0; mi < 2; ++mi) {
        int rbase = row0 + (2 * wave + mi) * 16 + q * 4;
        #pragma unroll
        for (int r = 0; r < 4; ++r) {
            int gr = rbase + r;
            if (gr < M) {
                #pragma unroll
                for (int nt = 0; nt < 8; ++nt)
                    C[gr * 128 + nt * 16 + mm] = acc[mi][nt][r];
            }
        }
    }
}

// ------------------------------------------- gather aggregation, fully fused
__global__ __launch_bounds__(256) void k_agg(const float* __restrict__ h,
                                             const int* __restrict__ off,
                                             const int* __restrict__ csr_src,
                                             const float* __restrict__ csr_w,
                                             const float* __restrict__ dinv,
                                             const float* __restrict__ bias,
                                             float* __restrict__ out,
                                             int N, int relu) {
    int n = (blockIdx.x * 256 + threadIdx.x) >> 6;
    if (n >= N) return;
    int l = threadIdx.x & 63;
    const float2* h2 = (const float2*)h;

    float di = dinv[n];
    float2 acc = h2[(n << 6) + l];          // self-loop term
    acc.x *= di * di;
    acc.y *= di * di;

    int e = off[n], end = off[n + 1];
    for (; e + 4 <= end; e += 4) {
        int s0 = csr_src[e + 0], s1 = csr_src[e + 1];
        int s2 = csr_src[e + 2], s3 = csr_src[e + 3];
        float w0 = csr_w[e + 0], w1 = csr_w[e + 1];
        float w2 = csr_w[e + 2], w3 = csr_w[e + 3];
        float2 v0 = h2[(s0 << 6) + l];
        float2 v1 = h2[(s1 << 6) + l];
        float2 v2 = h2[(s2 << 6) + l];
        float2 v3 = h2[(s3 << 6) + l];
        acc.x += w0 * v0.x + w1 * v1.x + w2 * v2.x + w3 * v3.x;
        acc.y += w0 * v0.y + w1 * v1.y + w2 * v2.y + w3 * v3.y;
    }
    for (; e < end; ++e) {
        int s = csr_src[e];
        float w = csr_w[e];
        float2 v = h2[(s << 6) + l];
        acc.x += w * v.x;
        acc.y += w * v.y;
    }

    float2 bv = ((const float2*)bias)[l];
    acc.x += bv.x;
    acc.y += bv.y;
    if (relu) {
        acc.x = fmaxf(acc.x, 0.f);
        acc.y = fmaxf(acc.y, 0.f);
    }
    ((float2*)out)[(n << 6) + l] = acc;
}

// ---------------------------------------------------------------- launch
extern "C" void kernel_launch(void* const* d_in, const int* in_sizes, int n_in,
                              void* d_out, int out_size, void* d_ws, size_t ws_size,
                              hipStream_t stream) {
    const float* x  = (const float*)d_in[0];
    const int*   ei = (const int*)d_in[1];
    const float* W1 = (const float*)d_in[2];
    const float* b1 = (const float*)d_in[3];
    const float* W2 = (const float*)d_in[4];
    const float* b2 = (const float*)d_in[5];
    float* out = (float*)d_out;

    const int N = in_sizes[0] / DIM;        // 100000
    const int E = in_sizes[1] / 2;          // 1600000
    const int* src = ei;
    const int* dst = ei + E;

    // workspace layout
    char* w = (char*)d_ws;
    float* dinv    = (float*)(w);                         // 400 KB
    int*   cnt     = (int*)  (w + (1 << 19));             // hist, then cursor
    int*   off     = (int*)  (w + (2 << 19));             // N+1 offsets
    int*   bsum    = (int*)  (w + (3 << 19));             // 2 KB
    short* whi     = (short*)(w + (3 << 19) + (1 << 16)); // 64 KB (2 layers)
    short* wlo     = whi + 2 * 16384;                     // 64 KB
    int*   csr_src = (int*)  (w + (4 << 19));             // 6.4 MB
    float* csr_w   = (float*)(w + (4 << 19) + (8 << 20)); // 6.4 MB
    float* buf_h   = (float*)(w + (4 << 19) + (16 << 20));             // 51.2 MB
    float* buf_a   = (float*)(w + (4 << 19) + (16 << 20) + ((size_t)N * DIM * 4));

    const int B = 256;
    const int nb = (N + 255) / 256;

    // CSR build + W fragment prep
    hipMemsetAsync(cnt, 0, (size_t)N * 4, stream);
    k_prep_w<<<16, B, 0, stream>>>(W1, W2, whi, wlo);
    k_hist<<<(E + B - 1) / B, B, 0, stream>>>(dst, cnt, E);
    k_dinv<<<nb, B, 0, stream>>>(cnt, dinv, N);
    k_scan1<<<nb, B, 0, stream>>>(cnt, off, bsum, N);
    k_scan2<<<1, 512, 0, stream>>>(bsum, nb);
    k_scan3<<<nb, B, 0, stream>>>(off, bsum, N, E);
    hipMemsetAsync(cnt, 0, (size_t)N * 4, stream);
    k_scatter<<<(E + B - 1) / B, B, 0, stream>>>(src, dst, off, cnt, dinv,
                                                 csr_src, csr_w, E);

    const int gemm_grid = (N + 127) / 128;
    const int agg_grid = (N * 64 + B - 1) / B;

    // layer 1
    k_gemm<<<gemm_grid, B, 0, stream>>>(x, whi, wlo, buf_h, N);
    k_agg<<<agg_grid, B, 0, stream>>>(buf_h, off, csr_src, csr_w, dinv, b1,
                                      buf_a, N, 1);
    // layer 2
    k_gemm<<<gemm_grid, B, 0, stream>>>(buf_a, whi + 16384, wlo + 16384,
                                        buf_h, N);
    k_agg<<<agg_grid, B, 0, stream>>>(buf_h, off, csr_src, csr_w, dinv, b2,
                                      out, N, 0);
}

// Round 4
// 493.413 us; speedup vs baseline: 11.6912x; 1.1400x over previous
//
#include <hip/hip_runtime.h>

// GCN 2-layer forward, MI355X round 3:
//  - h stored bf16 (gather stream halved: agg is L2-miss-byte-bound)
//  - A pre-split to fragment-ready hi/lo bf16 by producers (prep_x / agg1 epilogue)
//  - GEMM stages via global_load_lds(16B) -> zero staging VALU, bf16 output
// Pipeline: memset -> prep(W+x) -> hist -> scan(+dinv) -> scatter ->
//           GEMM1 -> agg1(frag out) -> GEMM2 -> agg2(fp32 out)

#define DIM 128
typedef unsigned short ushort_t;
typedef unsigned int uint_t;
typedef __attribute__((ext_vector_type(8))) short bf16x8;
typedef __attribute__((ext_vector_type(4))) float f32x4;

static __device__ __forceinline__ uint_t f2bf(float f) {
    union { float f; uint_t u; } c; c.f = f;
    uint_t u = c.u;
    return (u + 0x7FFFu + ((u >> 16) & 1u)) >> 16;   // round-nearest
}
static __device__ __forceinline__ float bf2f(uint_t h) {
    union { uint_t u; float f; } c; c.u = h << 16;
    return c.f;
}
static __device__ __forceinline__ float as_f(uint_t u) {
    union { uint_t u; float f; } c; c.u = u;
    return c.f;
}
static __device__ __forceinline__ void gld16(const void* g, void* l) {
    __builtin_amdgcn_global_load_lds(
        (const __attribute__((address_space(1))) uint_t*)g,
        (__attribute__((address_space(3))) uint_t*)l, 16, 0, 0);
}

// ---------------------------------------------------------------- histogram
__global__ __launch_bounds__(256) void k_hist(const int* __restrict__ dst,
                                              int* __restrict__ cnt, int E) {
    int e = blockIdx.x * 256 + threadIdx.x;
    if (e < E) atomicAdd(&cnt[dst[e]], 1);
}

// ------------------------------------------------- scan (fused dinv)
__global__ __launch_bounds__(256) void k_scan1(const int* __restrict__ cnt,
                                               int* __restrict__ off,
                                               int* __restrict__ bsum,
                                               float* __restrict__ dinv, int n) {
    __shared__ int s[256];
    int t = threadIdx.x;
    int i = blockIdx.x * 256 + t;
    int v = (i < n) ? cnt[i] : 0;
    if (i < n) dinv[i] = rsqrtf((float)v + 1.0f);   // +1 self-loop
    s[t] = v;
    __syncthreads();
    #pragma unroll
    for (int o = 1; o < 256; o <<= 1) {
        int x = (t >= o) ? s[t - o] : 0;
        __syncthreads();
        s[t] += x;
        __syncthreads();
    }
    if (i < n) off[i] = s[t] - v;
    if (t == 0) bsum[blockIdx.x] = s[255];
}

__global__ __launch_bounds__(512) void k_scan2(int* __restrict__ bsum, int nb) {
    __shared__ int s[512];
    int t = threadIdx.x;
    int v = (t < nb) ? bsum[t] : 0;
    s[t] = v;
    __syncthreads();
    #pragma unroll
    for (int o = 1; o < 512; o <<= 1) {
        int x = (t >= o) ? s[t - o] : 0;
        __syncthreads();
        s[t] += x;
        __syncthreads();
    }
    if (t < nb) bsum[t] = s[t] - v;
}

__global__ __launch_bounds__(256) void k_scan3(int* __restrict__ off,
                                               const int* __restrict__ bsum,
                                               int n, int E) {
    int i = blockIdx.x * 256 + threadIdx.x;
    if (i < n) off[i] += bsum[blockIdx.x];
    if (i == 0) off[n] = E;
}

// ---------------------------------------------------- bucket scatter to CSR
__global__ __launch_bounds__(256) void k_scatter(const int* __restrict__ src,
                                                 const int* __restrict__ dst,
                                                 const int* __restrict__ off,
                                                 int* __restrict__ cur,
                                                 const float* __restrict__ dinv,
                                                 int* __restrict__ csr_src,
                                                 float* __restrict__ csr_w, int E) {
    int e = blockIdx.x * 256 + threadIdx.x;
    if (e >= E) return;
    int s = src[e], d = dst[e];
    int pos = off[d] + atomicAdd(&cur[d], 1);
    csr_src[pos] = s;
    csr_w[pos] = dinv[s] * dinv[d];
}

// ------------------------------------- prep: W frags + x frags (hi/lo bf16)
// frag chunk layout (16B = 8 bf16): chunk = ((rb*4+kslab)*8 + p)*64 + lane
//   holds A[row = rb*128+p*16+(lane&15)][k = kslab*32+(lane>>4)*8 + j], j=0..7
// W chunk: ((layer*4+kslab)*8 + nt)*64 + lane -> B[k][n = nt*16+(lane&15)]
__global__ __launch_bounds__(256) void k_prep(const float* __restrict__ W1,
                                              const float* __restrict__ W2,
                                              const float* __restrict__ x,
                                              short* __restrict__ whi,
                                              short* __restrict__ wlo,
                                              short* __restrict__ xhi,
                                              short* __restrict__ xlo,
                                              int N, int nxc) {
    int t = threadIdx.x;
    if (blockIdx.x < 16) {                       // ---- W part: 4096 chunks
        int g = blockIdx.x * 256 + t;
        int layer = g >> 11, c = g & 2047;
        const float* W = layer ? W2 : W1;
        int ks = c >> 9, nt = (c >> 6) & 7, l = c & 63;
        int q = l >> 4, m = l & 15;
        int n = nt * 16 + m;
        bf16x8 h8, l8;
        #pragma unroll
        for (int j = 0; j < 8; ++j) {
            int k = ks * 32 + q * 8 + j;
            float f = W[k * 128 + n];
            uint_t hb = f2bf(f);
            h8[j] = (short)hb;
            l8[j] = (short)f2bf(f - bf2f(hb));
        }
        ((bf16x8*)whi)[g] = h8;
        ((bf16x8*)wlo)[g] = l8;
    } else {                                     // ---- X part
        int c = (blockIdx.x - 16) * 256 + t;
        if (c >= nxc) return;
        int lane = c & 63, p = (c >> 6) & 7, kslab = (c >> 9) & 3, rb = c >> 11;
        int row = rb * 128 + p * 16 + (lane & 15);
        int k0 = kslab * 32 + (lane >> 4) * 8;
        bf16x8 h8 = {}, l8 = {};
        if (row < N) {
            float4 fa = ((const float4*)x)[row * 32 + (k0 >> 2)];
            float4 fb = ((const float4*)x)[row * 32 + (k0 >> 2) + 1];
            float f[8] = {fa.x, fa.y, fa.z, fa.w, fb.x, fb.y, fb.z, fb.w};
            #pragma unroll
            for (int j = 0; j < 8; ++j) {
                uint_t hb = f2bf(f[j]);
                h8[j] = (short)hb;
                l8[j] = (short)f2bf(f[j] - bf2f(hb));
            }
        }
        ((bf16x8*)xhi)[c] = h8;
        ((bf16x8*)xlo)[c] = l8;
    }
}

// ------------------------------------------------- split-bf16 MFMA GEMM
// 256 thr / 128 rows per block; K in 2 staged halves via global_load_lds(16B).
// Wave tile 64 rows x 64 cols (acc 4x4). Output written as bf16 row-major.
__global__ __launch_bounds__(256) void k_gemm(const short* __restrict__ afhi,
                                              const short* __restrict__ aflo,
                                              const short* __restrict__ wfhi,
                                              const short* __restrict__ wflo,
                                              ushort_t* __restrict__ hout, int M) {
    __shared__ short AH[8192], AL[8192], WH[8192], WL[8192];   // 64 KB
    const int t = threadIdx.x;
    const int rb = blockIdx.x;
    const int wv = t >> 6, l = t & 63;
    const int mb = (wv & 1) * 4;        // mtile base (panel)
    const int nbc = (wv >> 1) * 4;      // ntile base

    f32x4 acc[4][4];
    #pragma unroll
    for (int i = 0; i < 4; ++i)
        #pragma unroll
        for (int j = 0; j < 4; ++j)
            acc[i][j] = (f32x4){0.f, 0.f, 0.f, 0.f};

    #pragma unroll
    for (int kc = 0; kc < 2; ++kc) {
        if (kc) __syncthreads();        // pass-0 LDS reads complete
        {
            const short* ga = afhi + (size_t)(rb * 4 + 2 * kc) * 4096;
            const short* gb = aflo + (size_t)(rb * 4 + 2 * kc) * 4096;
            const short* gh = wfhi + 2 * kc * 4096;
            const short* gl = wflo + 2 * kc * 4096;
            #pragma unroll
            for (int i = 0; i < 4; ++i) {
                int idx = (i * 256 + t) * 8;
                gld16(ga + idx, AH + idx);
                gld16(gb + idx, AL + idx);
                gld16(gh + idx, WH + idx);
                gld16(gl + idx, WL + idx);
            }
        }
        __syncthreads();                // vmcnt(0) drain: LDS populated
        #pragma unroll
        for (int ksl = 0; ksl < 2; ++ksl) {
            bf16x8 ah[4], al[4];
            #pragma unroll
            for (int i = 0; i < 4; ++i) {
                ah[i] = *(const bf16x8*)&AH[((ksl * 8 + mb + i) * 64 + l) * 8];
                al[i] = *(const bf16x8*)&AL[((ksl * 8 + mb + i) * 64 + l) * 8];
            }
            #pragma unroll
            for (int j = 0; j < 4; ++j) {
                bf16x8 bh = *(const bf16x8*)&WH[((ksl * 8 + nbc + j) * 64 + l) * 8];
                bf16x8 bl = *(const bf16x8*)&WL[((ksl * 8 + nbc + j) * 64 + l) * 8];
                #pragma unroll
                for (int i = 0; i < 4; ++i) {
                    acc[i][j] = __builtin_amdgcn_mfma_f32_16x16x32_bf16(ah[i], bh, acc[i][j], 0, 0, 0);
                    acc[i][j] = __builtin_amdgcn_mfma_f32_16x16x32_bf16(al[i], bh, acc[i][j], 0, 0, 0);
                    acc[i][j] = __builtin_amdgcn_mfma_f32_16x16x32_bf16(ah[i], bl, acc[i][j], 0, 0, 0);
                }
            }
        }
    }

    // C/D layout: col = lane&15, row = (lane>>4)*4 + reg
    const int q = l >> 4, mm = l & 15;
    #pragma unroll
    for (int i = 0; i < 4; ++i)
        #pragma unroll
        for (int r = 0; r < 4; ++r) {
            int gr = rb * 128 + (wv & 1) * 64 + i * 16 + q * 4 + r;
            if (gr < M) {
                #pragma unroll
                for (int j = 0; j < 4; ++j)
                    hout[gr * 128 + nbc * 16 + j * 16 + mm] =
                        (ushort_t)f2bf(acc[i][j][r]);
            }
        }
}

// ------------------------------------------- gather aggregation (bf16 h)
// One wave/node; lane l holds cols 2l, 2l+1 (one uint = 2 bf16).
// FRAG=1: write relu'd result as fragment-ready hi/lo bf16 (layer-2 GEMM input)
// FRAG=0: write fp32 to out.
template <int FRAG>
__global__ __launch_bounds__(256) void k_agg(const uint_t* __restrict__ h32,
                                             const int* __restrict__ off,
                                             const int* __restrict__ csr_src,
                                             const float* __restrict__ csr_w,
                                             const float* __restrict__ dinv,
                                             const float* __restrict__ bias,
                                             float* __restrict__ out,
                                             uint_t* __restrict__ fhi,
                                             uint_t* __restrict__ flo, int N) {
    int n = (blockIdx.x * 256 + threadIdx.x) >> 6;
    if (n >= N) return;
    int l = threadIdx.x & 63;

    float di = dinv[n];
    uint_t sv = h32[(n << 6) + l];
    float accx = as_f(sv << 16) * di * di;
    float accy = as_f(sv & 0xffff0000u) * di * di;

    int e = off[n], end = off[n + 1];
    for (; e + 8 <= end; e += 8) {
        int s[8]; float ww[8]; uint_t v[8];
        #pragma unroll
        for (int u = 0; u < 8; ++u) { s[u] = csr_src[e + u]; ww[u] = csr_w[e + u]; }
        #pragma unroll
        for (int u = 0; u < 8; ++u) v[u] = h32[(s[u] << 6) + l];
        #pragma unroll
        for (int u = 0; u < 8; ++u) {
            accx += ww[u] * as_f(v[u] << 16);
            accy += ww[u] * as_f(v[u] & 0xffff0000u);
        }
    }
    for (; e < end; ++e) {
        int s = csr_src[e];
        float w = csr_w[e];
        uint_t v = h32[(s << 6) + l];
        accx += w * as_f(v << 16);
        accy += w * as_f(v & 0xffff0000u);
    }

    float2 bv = ((const float2*)bias)[l];
    accx += bv.x;
    accy += bv.y;

    if (FRAG) {
        accx = fmaxf(accx, 0.f);
        accy = fmaxf(accy, 0.f);
        uint_t hx = f2bf(accx), hy = f2bf(accy);
        uint_t lx = f2bf(accx - bf2f(hx)), ly = f2bf(accy - bf2f(hy));
        // frag slot for (row n, cols 2l,2l+1); block's 4 nodes fill 64B lines
        int rb = n >> 7, kslab = l >> 4, p = (n >> 4) & 7;
        int lp = ((l >> 2) & 3) * 16 + (n & 15);
        int chunk = ((rb * 4 + kslab) * 8 + p) * 64 + lp;
        fhi[chunk * 4 + (l & 3)] = (hy << 16) | hx;
        flo[chunk * 4 + (l & 3)] = (ly << 16) | lx;
    } else {
        ((float2*)out)[(n << 6) + l] = make_float2(accx, accy);
    }
}

// ---------------------------------------------------------------- launch
extern "C" void kernel_launch(void* const* d_in, const int* in_sizes, int n_in,
                              void* d_out, int out_size, void* d_ws, size_t ws_size,
                              hipStream_t stream) {
    const float* x  = (const float*)d_in[0];
    const int*   ei = (const int*)d_in[1];
    const float* W1 = (const float*)d_in[2];
    const float* b1 = (const float*)d_in[3];
    const float* W2 = (const float*)d_in[4];
    const float* b2 = (const float*)d_in[5];
    float* out = (float*)d_out;

    const int N = in_sizes[0] / DIM;        // 100000
    const int E = in_sizes[1] / 2;          // 1600000
    const int* src = ei;
    const int* dst = ei + E;
    const int RB = (N + 127) / 128;         // 782 row blocks
    const int nxc = RB * 2048;              // frag chunks

    // workspace layout (peak ~95 MB)
    char* w = (char*)d_ws;
    float* dinv    = (float*)(w);                       // 400 KB
    int*   cnt     = (int*)  (w + (1 << 19));           // N ints
    int*   cur     = cnt + N;                           // N ints
    int*   off     = (int*)  (w + (3 << 19));           // N+1 ints
    int*   bsum    = (int*)  (w + (1 << 21));           // 2 KB
    short* whi     = (short*)(w + (1 << 21) + (1 << 13));
    short* wlo     = whi + 2 * 16384;                   // W frags 128 KB total
    int*   csr_src = (int*)  (w + ((size_t)5 << 19));   // 6.4 MB
    float* csr_w   = (float*)(w + ((size_t)10 << 20));  // 6.4 MB
    short* fhi     = (short*)(w + ((size_t)17 << 20));  // 25.6 MB (x_frag, then a_frag)
    short* flo     = (short*)(w + ((size_t)43 << 20));  // 25.6 MB
    ushort_t* hbuf = (ushort_t*)(w + ((size_t)69 << 20)); // 25.6 MB bf16 h

    const int B = 256;
    const int nb = (N + 255) / 256;
    const int agg_grid = (N * 64 + B - 1) / B;

    hipMemsetAsync(cnt, 0, (size_t)2 * N * 4, stream);  // hist cnt + scatter cur
    k_prep<<<16 + (nxc + B - 1) / B, B, 0, stream>>>(W1, W2, x, whi, wlo,
                                                     fhi, flo, N, nxc);
    k_hist<<<(E + B - 1) / B, B, 0, stream>>>(dst, cnt, E);
    k_scan1<<<nb, B, 0, stream>>>(cnt, off, bsum, dinv, N);
    k_scan2<<<1, 512, 0, stream>>>(bsum, nb);
    k_scan3<<<nb, B, 0, stream>>>(off, bsum, N, E);
    k_scatter<<<(E + B - 1) / B, B, 0, stream>>>(src, dst, off, cur, dinv,
                                                 csr_src, csr_w, E);
    // layer 1
    k_gemm<<<RB, B, 0, stream>>>(fhi, flo, whi, wlo, hbuf, N);
    k_agg<1><<<agg_grid, B, 0, stream>>>((const uint_t*)hbuf, off, csr_src,
                                         csr_w, dinv, b1, nullptr,
                                         (uint_t*)fhi, (uint_t*)flo, N);
    // layer 2
    k_gemm<<<RB, B, 0, stream>>>(fhi, flo, whi + 16384, wlo + 16384, hbuf, N);
    k_agg<0><<<agg_grid, B, 0, stream>>>((const uint_t*)hbuf, off, csr_src,
                                         csr_w, dinv, b2, out,
                                         nullptr, nullptr, N);
}

// Round 5
// 430.412 us; speedup vs baseline: 13.4025x; 1.1464x over previous
//
#include <hip/hip_runtime.h>

// GCN 2-layer forward, MI355X round 4:
//  - scatter de-fanged: rank precomputed in hist (atomic return), csr_w dropped
//    (agg recomputes w = dinv[s]*dinv[n], factoring dinv[n] out of the loop)
//    -> scatter = 1 random 4B store/edge, no atomics, half the dirty lines
//  - everything else unchanged from round 3 (bf16 gather, DMA-staged MFMA GEMM)

#define DIM 128
typedef unsigned short ushort_t;
typedef unsigned int uint_t;
typedef __attribute__((ext_vector_type(8))) short bf16x8;
typedef __attribute__((ext_vector_type(4))) float f32x4;

static __device__ __forceinline__ uint_t f2bf(float f) {
    union { float f; uint_t u; } c; c.f = f;
    uint_t u = c.u;
    return (u + 0x7FFFu + ((u >> 16) & 1u)) >> 16;   // round-nearest
}
static __device__ __forceinline__ float bf2f(uint_t h) {
    union { uint_t u; float f; } c; c.u = h << 16;
    return c.f;
}
static __device__ __forceinline__ float as_f(uint_t u) {
    union { uint_t u; float f; } c; c.u = u;
    return c.f;
}
static __device__ __forceinline__ void gld16(const void* g, void* l) {
    __builtin_amdgcn_global_load_lds(
        (const __attribute__((address_space(1))) uint_t*)g,
        (__attribute__((address_space(3))) uint_t*)l, 16, 0, 0);
}

// ------------------------------------------- histogram + per-edge rank
__global__ __launch_bounds__(256) void k_hist(const int* __restrict__ dst,
                                              int* __restrict__ cnt,
                                              int* __restrict__ rank, int E) {
    int e = blockIdx.x * 256 + threadIdx.x;
    if (e < E) rank[e] = atomicAdd(&cnt[dst[e]], 1);
}

// ------------------------------------------------- scan (fused dinv)
__global__ __launch_bounds__(256) void k_scan1(const int* __restrict__ cnt,
                                               int* __restrict__ off,
                                               int* __restrict__ bsum,
                                               float* __restrict__ dinv, int n) {
    __shared__ int s[256];
    int t = threadIdx.x;
    int i = blockIdx.x * 256 + t;
    int v = (i < n) ? cnt[i] : 0;
    if (i < n) dinv[i] = rsqrtf((float)v + 1.0f);   // +1 self-loop
    s[t] = v;
    __syncthreads();
    #pragma unroll
    for (int o = 1; o < 256; o <<= 1) {
        int x = (t >= o) ? s[t - o] : 0;
        __syncthreads();
        s[t] += x;
        __syncthreads();
    }
    if (i < n) off[i] = s[t] - v;
    if (t == 0) bsum[blockIdx.x] = s[255];
}

__global__ __launch_bounds__(512) void k_scan2(int* __restrict__ bsum, int nb) {
    __shared__ int s[512];
    int t = threadIdx.x;
    int v = (t < nb) ? bsum[t] : 0;
    s[t] = v;
    __syncthreads();
    #pragma unroll
    for (int o = 1; o < 512; o <<= 1) {
        int x = (t >= o) ? s[t - o] : 0;
        __syncthreads();
        s[t] += x;
        __syncthreads();
    }
    if (t < nb) bsum[t] = s[t] - v;
}

__global__ __launch_bounds__(256) void k_scan3(int* __restrict__ off,
                                               const int* __restrict__ bsum,
                                               int n, int E) {
    int i = blockIdx.x * 256 + threadIdx.x;
    if (i < n) off[i] += bsum[blockIdx.x];
    if (i == 0) off[n] = E;
}

// ------------------------------- bucket scatter: no atomics, 1 store/edge
__global__ __launch_bounds__(256) void k_scatter(const int* __restrict__ src,
                                                 const int* __restrict__ dst,
                                                 const int* __restrict__ rank,
                                                 const int* __restrict__ off,
                                                 int* __restrict__ csr_src, int E) {
    int e = blockIdx.x * 256 + threadIdx.x;
    if (e >= E) return;
    int d = dst[e];
    csr_src[off[d] + rank[e]] = src[e];
}

// ------------------------------------- prep: W frags + x frags (hi/lo bf16)
// frag chunk layout (16B = 8 bf16): chunk = ((rb*4+kslab)*8 + p)*64 + lane
//   holds A[row = rb*128+p*16+(lane&15)][k = kslab*32+(lane>>4)*8 + j], j=0..7
// W chunk: ((layer*4+kslab)*8 + nt)*64 + lane -> B[k][n = nt*16+(lane&15)]
__global__ __launch_bounds__(256) void k_prep(const float* __restrict__ W1,
                                              const float* __restrict__ W2,
                                              const float* __restrict__ x,
                                              short* __restrict__ whi,
                                              short* __restrict__ wlo,
                                              short* __restrict__ xhi,
                                              short* __restrict__ xlo,
                                              int N, int nxc) {
    int t = threadIdx.x;
    if (blockIdx.x < 16) {                       // ---- W part: 4096 chunks
        int g = blockIdx.x * 256 + t;
        int layer = g >> 11, c = g & 2047;
        const float* W = layer ? W2 : W1;
        int ks = c >> 9, nt = (c >> 6) & 7, l = c & 63;
        int q = l >> 4, m = l & 15;
        int n = nt * 16 + m;
        bf16x8 h8, l8;
        #pragma unroll
        for (int j = 0; j < 8; ++j) {
            int k = ks * 32 + q * 8 + j;
            float f = W[k * 128 + n];
            uint_t hb = f2bf(f);
            h8[j] = (short)hb;
            l8[j] = (short)f2bf(f - bf2f(hb));
        }
        ((bf16x8*)whi)[g] = h8;
        ((bf16x8*)wlo)[g] = l8;
    } else {                                     // ---- X part
        int c = (blockIdx.x - 16) * 256 + t;
        if (c >= nxc) return;
        int lane = c & 63, p = (c >> 6) & 7, kslab = (c >> 9) & 3, rb = c >> 11;
        int row = rb * 128 + p * 16 + (lane & 15);
        int k0 = kslab * 32 + (lane >> 4) * 8;
        bf16x8 h8 = {}, l8 = {};
        if (row < N) {
            float4 fa = ((const float4*)x)[row * 32 + (k0 >> 2)];
            float4 fb = ((const float4*)x)[row * 32 + (k0 >> 2) + 1];
            float f[8] = {fa.x, fa.y, fa.z, fa.w, fb.x, fb.y, fb.z, fb.w};
            #pragma unroll
            for (int j = 0; j < 8; ++j) {
                uint_t hb = f2bf(f[j]);
                h8[j] = (short)hb;
                l8[j] = (short)f2bf(f[j] - bf2f(hb));
            }
        }
        ((bf16x8*)xhi)[c] = h8;
        ((bf16x8*)xlo)[c] = l8;
    }
}

// ------------------------------------------------- split-bf16 MFMA GEMM
// 256 thr / 128 rows per block; K in 2 staged halves via global_load_lds(16B).
// Wave tile 64 rows x 64 cols (acc 4x4). Output written as bf16 row-major.
__global__ __launch_bounds__(256) void k_gemm(const short* __restrict__ afhi,
                                              const short* __restrict__ aflo,
                                              const short* __restrict__ wfhi,
                                              const short* __restrict__ wflo,
                                              ushort_t* __restrict__ hout, int M) {
    __shared__ short AH[8192], AL[8192], WH[8192], WL[8192];   // 64 KB
    const int t = threadIdx.x;
    const int rb = blockIdx.x;
    const int wv = t >> 6, l = t & 63;
    const int mb = (wv & 1) * 4;        // mtile base (panel)
    const int nbc = (wv >> 1) * 4;      // ntile base

    f32x4 acc[4][4];
    #pragma unroll
    for (int i = 0; i < 4; ++i)
        #pragma unroll
        for (int j = 0; j < 4; ++j)
            acc[i][j] = (f32x4){0.f, 0.f, 0.f, 0.f};

    #pragma unroll
    for (int kc = 0; kc < 2; ++kc) {
        if (kc) __syncthreads();        // pass-0 LDS reads complete
        {
            const short* ga = afhi + (size_t)(rb * 4 + 2 * kc) * 4096;
            const short* gb = aflo + (size_t)(rb * 4 + 2 * kc) * 4096;
            const short* gh = wfhi + 2 * kc * 4096;
            const short* gl = wflo + 2 * kc * 4096;
            #pragma unroll
            for (int i = 0; i < 4; ++i) {
                int idx = (i * 256 + t) * 8;
                gld16(ga + idx, AH + idx);
                gld16(gb + idx, AL + idx);
                gld16(gh + idx, WH + idx);
                gld16(gl + idx, WL + idx);
            }
        }
        __syncthreads();                // vmcnt(0) drain: LDS populated
        #pragma unroll
        for (int ksl = 0; ksl < 2; ++ksl) {
            bf16x8 ah[4], al[4];
            #pragma unroll
            for (int i = 0; i < 4; ++i) {
                ah[i] = *(const bf16x8*)&AH[((ksl * 8 + mb + i) * 64 + l) * 8];
                al[i] = *(const bf16x8*)&AL[((ksl * 8 + mb + i) * 64 + l) * 8];
            }
            #pragma unroll
            for (int j = 0; j < 4; ++j) {
                bf16x8 bh = *(const bf16x8*)&WH[((ksl * 8 + nbc + j) * 64 + l) * 8];
                bf16x8 bl = *(const bf16x8*)&WL[((ksl * 8 + nbc + j) * 64 + l) * 8];
                #pragma unroll
                for (int i = 0; i < 4; ++i) {
                    acc[i][j] = __builtin_amdgcn_mfma_f32_16x16x32_bf16(ah[i], bh, acc[i][j], 0, 0, 0);
                    acc[i][j] = __builtin_amdgcn_mfma_f32_16x16x32_bf16(al[i], bh, acc[i][j], 0, 0, 0);
                    acc[i][j] = __builtin_amdgcn_mfma_f32_16x16x32_bf16(ah[i], bl, acc[i][j], 0, 0, 0);
                }
            }
        }
    }

    // C/D layout: col = lane&15, row = (lane>>4)*4 + reg
    const int q = l >> 4, mm = l & 15;
    #pragma unroll
    for (int i = 0; i < 4; ++i)
        #pragma unroll
        for (int r = 0; r < 4; ++r) {
            int gr = rb * 128 + (wv & 1) * 64 + i * 16 + q * 4 + r;
            if (gr < M) {
                #pragma unroll
                for (int j = 0; j < 4; ++j)
                    hout[gr * 128 + nbc * 16 + j * 16 + mm] =
                        (ushort_t)f2bf(acc[i][j][r]);
            }
        }
}

// ------------------------------------------- gather aggregation (bf16 h)
// One wave/node; lane l holds cols 2l, 2l+1 (one uint = 2 bf16).
// acc = Sum dinv[s]*h[s]; out = di*(acc + di*h[n]) + bias  (di = dinv[n])
// FRAG=1: write relu'd result as fragment-ready hi/lo bf16 (layer-2 GEMM input)
// FRAG=0: write fp32 to out.
template <int FRAG>
__global__ __launch_bounds__(256) void k_agg(const uint_t* __restrict__ h32,
                                             const int* __restrict__ off,
                                             const int* __restrict__ csr_src,
                                             const float* __restrict__ dinv,
                                             const float* __restrict__ bias,
                                             float* __restrict__ out,
                                             uint_t* __restrict__ fhi,
                                             uint_t* __restrict__ flo, int N) {
    int n = (blockIdx.x * 256 + threadIdx.x) >> 6;
    if (n >= N) return;
    int l = threadIdx.x & 63;

    float di = dinv[n];
    uint_t sv = h32[(n << 6) + l];
    float accx = as_f(sv << 16) * di;          // becomes di^2 * self after final scale
    float accy = as_f(sv & 0xffff0000u) * di;

    int e = off[n], end = off[n + 1];
    for (; e + 8 <= end; e += 8) {
        int s[8]; float ws[8]; uint_t v[8];
        #pragma unroll
        for (int u = 0; u < 8; ++u) s[u] = csr_src[e + u];
        #pragma unroll
        for (int u = 0; u < 8; ++u) { ws[u] = dinv[s[u]]; v[u] = h32[(s[u] << 6) + l]; }
        #pragma unroll
        for (int u = 0; u < 8; ++u) {
            accx += ws[u] * as_f(v[u] << 16);
            accy += ws[u] * as_f(v[u] & 0xffff0000u);
        }
    }
    for (; e < end; ++e) {
        int s = csr_src[e];
        float w = dinv[s];
        uint_t v = h32[(s << 6) + l];
        accx += w * as_f(v << 16);
        accy += w * as_f(v & 0xffff0000u);
    }

    float2 bv = ((const float2*)bias)[l];
    accx = di * accx + bv.x;
    accy = di * accy + bv.y;

    if (FRAG) {
        accx = fmaxf(accx, 0.f);
        accy = fmaxf(accy, 0.f);
        uint_t hx = f2bf(accx), hy = f2bf(accy);
        uint_t lx = f2bf(accx - bf2f(hx)), ly = f2bf(accy - bf2f(hy));
        // frag slot for (row n, cols 2l,2l+1); block's 4 nodes fill 64B lines
        int rb = n >> 7, kslab = l >> 4, p = (n >> 4) & 7;
        int lp = ((l >> 2) & 3) * 16 + (n & 15);
        int chunk = ((rb * 4 + kslab) * 8 + p) * 64 + lp;
        fhi[chunk * 4 + (l & 3)] = (hy << 16) | hx;
        flo[chunk * 4 + (l & 3)] = (ly << 16) | lx;
    } else {
        ((float2*)out)[(n << 6) + l] = make_float2(accx, accy);
    }
}

// ---------------------------------------------------------------- launch
extern "C" void kernel_launch(void* const* d_in, const int* in_sizes, int n_in,
                              void* d_out, int out_size, void* d_ws, size_t ws_size,
                              hipStream_t stream) {
    const float* x  = (const float*)d_in[0];
    const int*   ei = (const int*)d_in[1];
    const float* W1 = (const float*)d_in[2];
    const float* b1 = (const float*)d_in[3];
    const float* W2 = (const float*)d_in[4];
    const float* b2 = (const float*)d_in[5];
    float* out = (float*)d_out;

    const int N = in_sizes[0] / DIM;        // 100000
    const int E = in_sizes[1] / 2;          // 1600000
    const int* src = ei;
    const int* dst = ei + E;
    const int RB = (N + 127) / 128;         // 782 row blocks
    const int nxc = RB * 2048;              // frag chunks

    // workspace layout (peak ~95 MB)
    char* w = (char*)d_ws;
    float* dinv    = (float*)(w);                       // 400 KB
    int*   cnt     = (int*)  (w + (1 << 19));           // N ints
    int*   off     = (int*)  (w + (3 << 19));           // N+1 ints
    int*   bsum    = (int*)  (w + (1 << 21));           // 2 KB
    short* whi     = (short*)(w + (1 << 21) + (1 << 13));
    short* wlo     = whi + 2 * 16384;                   // W frags 128 KB total
    int*   csr_src = (int*)  (w + ((size_t)5 << 19));   // 6.4 MB
    int*   rank    = (int*)  (w + ((size_t)10 << 20));  // 6.4 MB
    short* fhi     = (short*)(w + ((size_t)17 << 20));  // 25.6 MB (x_frag, then a_frag)
    short* flo     = (short*)(w + ((size_t)43 << 20));  // 25.6 MB
    ushort_t* hbuf = (ushort_t*)(w + ((size_t)69 << 20)); // 25.6 MB bf16 h

    const int B = 256;
    const int nb = (N + 255) / 256;
    const int agg_grid = (N * 64 + B - 1) / B;

    hipMemsetAsync(cnt, 0, (size_t)N * 4, stream);
    k_prep<<<16 + (nxc + B - 1) / B, B, 0, stream>>>(W1, W2, x, whi, wlo,
                                                     fhi, flo, N, nxc);
    k_hist<<<(E + B - 1) / B, B, 0, stream>>>(dst, cnt, rank, E);
    k_scan1<<<nb, B, 0, stream>>>(cnt, off, bsum, dinv, N);
    k_scan2<<<1, 512, 0, stream>>>(bsum, nb);
    k_scan3<<<nb, B, 0, stream>>>(off, bsum, N, E);
    k_scatter<<<(E + B - 1) / B, B, 0, stream>>>(src, dst, rank, off,
                                                 csr_src, E);
    // layer 1
    k_gemm<<<RB, B, 0, stream>>>(fhi, flo, whi, wlo, hbuf, N);
    k_agg<1><<<agg_grid, B, 0, stream>>>((const uint_t*)hbuf, off, csr_src,
                                         dinv, b1, nullptr,
                                         (uint_t*)fhi, (uint_t*)flo, N);
    // layer 2
    k_gemm<<<RB, B, 0, stream>>>(fhi, flo, whi + 16384, wlo + 16384, hbuf, N);
    k_agg<0><<<agg_grid, B, 0, stream>>>((const uint_t*)hbuf, off, csr_src,
                                         dinv, b2, out,
                                         nullptr, nullptr, N);
}